// Round 3
// baseline (514.752 us; speedup 1.0000x reference)
//
#include <hip/hip_runtime.h>
#include <hip/hip_bf16.h>
#include <stdint.h>

// ---------------------------------------------------------------------------
// ConvAttention (B=2,S=4096,HID=1024,H=16,HD=64; conv k=(4,1) stride=(4,1))
// Device dtypes: inputs float32, OUTPUTS float32 (round-2 forensics: logits
// bf16 writes aliased into output-0's f32 region -> error 8.97 ~= max|logits|).
// Compute internally in bf16 (threshold 0.26375 = 8*2^-8*8.44 permits it).
// Pipeline:
//   0. q f32 -> Xb bf16 [8192][1024]
//   1. convT: Wq,Wk,Wv,Wlin f32 [K][N] -> bf16 [N][K]
//   2. QKV = Xb @ W (head-major [bh][4096][64], bf16, ws)
//   3. depthwise conv K,V -> Kc,Vc [bh][1024][64] (bf16, ws)
//   4. transpose Vc -> Vct [bh][64][1024] (bf16, ws)
//   5. logits = Qh @ Kc^T * exp(-log_temp) -> f32 d_out[8388608..]  (output 1)
//   6. softmax rows (f32 read) + att @ Vc -> oattn bf16 (reuses Xb)
//   7. out = oattn @ Wlin -> f32 d_out[0..8388608)                  (output 0)
// GEMM: 128x128 tile, BK=64, 4 waves, global_load_lds 16B, 2-barrier loop
// (m97-verified structure).
// ---------------------------------------------------------------------------

using short8 = __attribute__((ext_vector_type(8))) short;
using f32x4  = __attribute__((ext_vector_type(4))) float;

__device__ __forceinline__ float bf2f(short u) {
  union { float f; uint32_t i; } v; v.i = ((uint32_t)(uint16_t)u) << 16; return v.f;
}
__device__ __forceinline__ short f2bf(float f) {
  union { float f; uint32_t i; } v; v.f = f;
  uint32_t r = v.i + 0x7FFFu + ((v.i >> 16) & 1u);   // RNE
  return (short)(uint16_t)(r >> 16);
}

__device__ __forceinline__ void async16(const void* g, void* l) {
  __builtin_amdgcn_global_load_lds(
      (const __attribute__((address_space(1))) void*)g,
      (__attribute__((address_space(3))) void*)l, 16, 0, 0);
}

// ---------------------------------------------------------------------------
// f32 -> bf16 elementwise, 8 elems/thread
__global__ void cvt8(const float* __restrict__ in, short* __restrict__ out) {
  const size_t i = ((size_t)blockIdx.x * 256 + threadIdx.x) * 8;
  float4 a = *(const float4*)(in + i);
  float4 b = *(const float4*)(in + i + 4);
  short8 o;
  o[0] = f2bf(a.x); o[1] = f2bf(a.y); o[2] = f2bf(a.z); o[3] = f2bf(a.w);
  o[4] = f2bf(b.x); o[5] = f2bf(b.y); o[6] = f2bf(b.z); o[7] = f2bf(b.w);
  *(short8*)(out + i) = o;
}

// ---------------------------------------------------------------------------
// fused convert+transpose: f32 in [R][C] -> bf16 out [C][R]
__global__ void convT(const float* __restrict__ in, short* __restrict__ out,
                      int R, int C) {
  __shared__ float tile[64][65];
  const int c0 = blockIdx.x * 64, r0 = blockIdx.y * 64;
  const int tx = threadIdx.x & 63, ty = threadIdx.x >> 6;
  #pragma unroll
  for (int i = ty; i < 64; i += 4)
    tile[i][tx] = in[(size_t)(r0 + i) * C + c0 + tx];
  __syncthreads();
  #pragma unroll
  for (int i = ty; i < 64; i += 4)
    out[(size_t)(c0 + i) * R + r0 + tx] = f2bf(tile[tx][i]);
}

// ---------------------------------------------------------------------------
// bf16 2D transpose: in [R][C] -> out [C][R], z batches of R*C
__global__ void transpose2d(const short* __restrict__ in, short* __restrict__ out,
                            int R, int C) {
  __shared__ short tile[64][65];
  const size_t zoff = (size_t)blockIdx.z * (size_t)R * (size_t)C;
  const int c0 = blockIdx.x * 64, r0 = blockIdx.y * 64;
  const int tx = threadIdx.x & 63, ty = threadIdx.x >> 6;
  #pragma unroll
  for (int i = ty; i < 64; i += 4)
    tile[i][tx] = in[zoff + (size_t)(r0 + i) * C + c0 + tx];
  __syncthreads();
  #pragma unroll
  for (int i = ty; i < 64; i += 4)
    out[zoff + (size_t)(c0 + i) * R + r0 + tx] = tile[tx][i];
}

// ---------------------------------------------------------------------------
// depthwise conv, stride 4, taps 4 along S. input head-major [bh][4096][64]
// (K at sel=0, V at sel=1 offset +8388608). out [bh][1024][64]. cw f32 [16][4].
__global__ void dwconv(const short* __restrict__ kv_hm, const float* __restrict__ cw,
                       short* __restrict__ kc, short* __restrict__ vc) {
  const int idx = blockIdx.x * 256 + threadIdx.x;   // 2*32*1024*64 = 4194304
  const int d   = idx & 63;
  const int sk  = (idx >> 6) & 1023;
  const int bh  = (idx >> 16) & 31;
  const int sel = idx >> 21;
  const int h   = bh & 15;
  const short* src = kv_hm + (size_t)sel * 8388608 + (size_t)bh * 262144
                   + (size_t)(4 * sk) * 64 + d;
  float acc = 0.f;
  #pragma unroll
  for (int i = 0; i < 4; ++i)
    acc += cw[h * 4 + i] * bf2f(src[i * 64]);
  short* dst = sel ? vc : kc;
  dst[(size_t)bh * 65536 + (size_t)sk * 64 + d] = f2bf(acc);
}

// ---------------------------------------------------------------------------
// C = A[M][K] * Bt[N][K]^T, bf16 inputs, f32 accum.
// mode 0: f32 row-major store to Cf. mode 1: bf16 head-major store to C.
struct GemmArgs {
  const short* A; const short* Bt;
  short* C;                 // bf16 out (mode 1)
  float* Cf;                // f32 out (mode 0)
  long sA, sB, sC;          // row strides (elems)
  long zA, zB, zC;          // per-blockIdx.z offsets (elems)
  int  K;
  const float* ltemp;       // if nonnull: scale C by exp(-ltemp[0])
  int  mode;
};

__global__ __launch_bounds__(256, 2)
void gemm_bt(GemmArgs g) {
  const int tid  = threadIdx.x;
  const int wave = tid >> 6, lane = tid & 63;
  const int l16 = lane & 15, l4 = lane >> 4;
  const int wm = wave & 1, wn = wave >> 1;
  const int m0 = blockIdx.y * 128, n0 = blockIdx.x * 128;
  const size_t zA = (size_t)blockIdx.z * g.zA;
  const size_t zB = (size_t)blockIdx.z * g.zB;
  const size_t zC = (size_t)blockIdx.z * g.zC;

  __shared__ __align__(16) short As[128 * 64];
  __shared__ __align__(16) short Bs[128 * 64];

  f32x4 acc[4][4] = {};

  const int srow = tid >> 3;            // 0..31
  const int scol = (tid & 7) << 3;      // 0,8,..,56
  const short* Abase = g.A + zA + (size_t)m0 * g.sA + scol;
  const short* Bbase = g.Bt + zB + (size_t)n0 * g.sB + scol;

  for (int k0 = 0; k0 < g.K; k0 += 64) {
    __syncthreads();                    // LDS reuse fence
    #pragma unroll
    for (int c = 0; c < 4; ++c) {
      async16(Abase + (size_t)(c * 32 + srow) * g.sA + k0, &As[c * 2048 + wave * 512]);
      async16(Bbase + (size_t)(c * 32 + srow) * g.sB + k0, &Bs[c * 2048 + wave * 512]);
    }
    asm volatile("s_waitcnt vmcnt(0)" ::: "memory");
    __syncthreads();
    #pragma unroll
    for (int kk = 0; kk < 2; ++kk) {
      short8 a[4], b[4];
      #pragma unroll
      for (int t = 0; t < 4; ++t) {
        a[t] = *(const short8*)&As[(wm * 64 + t * 16 + l16) * 64 + kk * 32 + l4 * 8];
        b[t] = *(const short8*)&Bs[(wn * 64 + t * 16 + l16) * 64 + kk * 32 + l4 * 8];
      }
      #pragma unroll
      for (int i = 0; i < 4; ++i)
        #pragma unroll
        for (int j = 0; j < 4; ++j)
          acc[i][j] = __builtin_amdgcn_mfma_f32_16x16x32_bf16(a[i], b[j], acc[i][j], 0, 0, 0);
    }
  }

  float sc = 1.0f;
  if (g.ltemp) sc = __expf(-g.ltemp[0]);

  if (g.mode == 0) {
    float* Cz = g.Cf + zC;
    #pragma unroll
    for (int i = 0; i < 4; ++i) {
      const int row = m0 + wm * 64 + i * 16 + l4 * 4;
      #pragma unroll
      for (int j = 0; j < 4; ++j) {
        const int col = n0 + wn * 64 + j * 16 + l16;
        #pragma unroll
        for (int rr = 0; rr < 4; ++rr)
          Cz[(size_t)(row + rr) * g.sC + col] = acc[i][j][rr] * sc;
      }
    }
  } else {
    // head-major bf16: off = (b*16+h)*262144 + q*64 + d ; b=m>>12, q=m&4095
    short* Cz = g.C + zC;
    #pragma unroll
    for (int i = 0; i < 4; ++i) {
      const int row = m0 + wm * 64 + i * 16 + l4 * 4;
      #pragma unroll
      for (int j = 0; j < 4; ++j) {
        const int col = n0 + wn * 64 + j * 16 + l16;
        const int hh = col >> 6, dd = col & 63;
        #pragma unroll
        for (int rr = 0; rr < 4; ++rr) {
          const int m = row + rr;
          const size_t off = (size_t)((m >> 12) * 16 + hh) * 262144
                           + (size_t)(m & 4095) * 64 + dd;
          Cz[off] = f2bf(acc[i][j][rr]);
        }
      }
    }
  }
}

// ---------------------------------------------------------------------------
// softmax over rows of f32 logits tile [32][1024] + PV gemm (att @ Vc).
// block = 256 thr (4 waves), grid = (4096/32, 32 bh).
__global__ __launch_bounds__(256, 2)
void softmax_pv(const float* __restrict__ logits, const short* __restrict__ vct,
                short* __restrict__ outp) {
  const int bh = blockIdx.y, q0 = blockIdx.x * 32;
  const int tid = threadIdx.x;
  const int b = bh >> 4, h = bh & 15;

  __shared__ __align__(16) short att[32][1032];   // padded: 2-way banks only
  __shared__ float red[32][8];
  __shared__ float rowmax[32], rowsum[32];

  const int r = tid >> 3, seg = tid & 7;          // 8 threads/row, 128 elems each
  const float* lg = logits + (size_t)bh * 4194304
                  + (size_t)(q0 + r) * 1024 + seg * 128;

  // pass a: load 128 f32 logits, f32 row max, keep bf16-rounded in regs
  short8 buf[16];
  float mx = -3.4e38f;
  #pragma unroll
  for (int u = 0; u < 16; ++u) {
    float4 a = *(const float4*)(lg + u * 8);
    float4 c = *(const float4*)(lg + u * 8 + 4);
    mx = fmaxf(mx, fmaxf(fmaxf(a.x, a.y), fmaxf(a.z, a.w)));
    mx = fmaxf(mx, fmaxf(fmaxf(c.x, c.y), fmaxf(c.z, c.w)));
    short8 o;
    o[0] = f2bf(a.x); o[1] = f2bf(a.y); o[2] = f2bf(a.z); o[3] = f2bf(a.w);
    o[4] = f2bf(c.x); o[5] = f2bf(c.y); o[6] = f2bf(c.z); o[7] = f2bf(c.w);
    buf[u] = o;
  }
  red[r][seg] = mx;
  __syncthreads();
  if (tid < 32) {
    float m = red[tid][0];
    #pragma unroll
    for (int i = 1; i < 8; ++i) m = fmaxf(m, red[tid][i]);
    rowmax[tid] = m;
  }
  __syncthreads();

  // pass b: e = exp(x - rowmax) -> att (bf16), row sum
  const float rm = rowmax[r];
  float sm = 0.f;
  #pragma unroll
  for (int u = 0; u < 16; ++u) {
    short8 v = buf[u], o;
    #pragma unroll
    for (int e = 0; e < 8; ++e) {
      float ev = __expf(bf2f(v[e]) - rm);
      sm += ev;
      o[e] = f2bf(ev);
    }
    *(short8*)&att[r][seg * 128 + u * 8] = o;
  }
  red[r][seg] = sm;
  __syncthreads();
  if (tid < 32) {
    float s = 0.f;
    #pragma unroll
    for (int i = 0; i < 8; ++i) s += red[tid][i];
    rowsum[tid] = s;
  }
  __syncthreads();

  // pass c: PV. wave -> (mt = wave&1, n-half = (wave>>1)*32), acc 16x32
  const int wave = tid >> 6, lane = tid & 63;
  const int l16 = lane & 15, l4 = lane >> 4;
  const int mt = wave & 1;
  const int n0 = (wave >> 1) * 32;
  const short* vb = vct + (size_t)bh * 64 * 1024;
  f32x4 acc0 = {}, acc1 = {};
  #pragma unroll 4
  for (int kk = 0; kk < 32; ++kk) {
    short8 a  = *(const short8*)&att[mt * 16 + l16][kk * 32 + l4 * 8];
    short8 b0 = *(const short8*)(vb + (size_t)(n0 + l16) * 1024 + kk * 32 + l4 * 8);
    short8 b1 = *(const short8*)(vb + (size_t)(n0 + 16 + l16) * 1024 + kk * 32 + l4 * 8);
    acc0 = __builtin_amdgcn_mfma_f32_16x16x32_bf16(a, b0, acc0, 0, 0, 0);
    acc1 = __builtin_amdgcn_mfma_f32_16x16x32_bf16(a, b1, acc1, 0, 0, 0);
  }
  short* op = outp + ((size_t)b * 4096 + q0) * 1024 + h * 64;
  #pragma unroll
  for (int rr = 0; rr < 4; ++rr) {
    const int row = mt * 16 + l4 * 4 + rr;
    const float inv = 1.0f / rowsum[row];
    op[(size_t)row * 1024 + n0 + l16]      = f2bf(acc0[rr] * inv);
    op[(size_t)row * 1024 + n0 + 16 + l16] = f2bf(acc1[rr] * inv);
  }
}

// ---------------------------------------------------------------------------
extern "C" void kernel_launch(void* const* d_in, const int* in_sizes, int n_in,
                              void* d_out, int out_size, void* d_ws, size_t ws_size,
                              hipStream_t stream) {
  const float* q    = (const float*)d_in[0];   // [8192][1024] f32
  const float* Wq   = (const float*)d_in[1];
  const float* Wk   = (const float*)d_in[2];
  const float* Wv   = (const float*)d_in[3];
  const float* Wlin = (const float*)d_in[4];
  const float* cw   = (const float*)d_in[5];   // [16][4] f32
  const float* lt   = (const float*)d_in[6];   // log_temp f32 scalar

  float* out_f    = (float*)d_out;             // output 0: [8192][1024] f32
  float* logits_f = out_f + 8388608;           // output 1: [32][4096][1024] f32

  short* ws   = (short*)d_ws;
  short* Wt   = ws;                  // 4 x 1048576 (Wq_t,Wk_t,Wv_t,Wlin_t)
  short* Xb   = ws + 4194304;        // 8388608 bf16(q); reused as oattn later
  short* QKV  = ws + 12582912;       // 3 x 8388608 head-major [bh][4096][64]
  short* Kc   = ws + 37748736;       // [32][1024][64]
  short* Vc   = ws + 39845888;       // [32][1024][64]
  short* Vct  = ws + 41943040;       // [32][64][1024]
  short* oattn = Xb;                 // Xb dead after QKV gemm
  // total: 44,040,192 shorts = 88.1 MB

  // 0. q -> bf16
  cvt8<<<dim3(4096), 256, 0, stream>>>(q, Xb);

  // 1. weight convert+transpose -> bf16 [N][K]
  convT<<<dim3(16, 16), 256, 0, stream>>>(Wq,   Wt,           1024, 1024);
  convT<<<dim3(16, 16), 256, 0, stream>>>(Wk,   Wt + 1048576, 1024, 1024);
  convT<<<dim3(16, 16), 256, 0, stream>>>(Wv,   Wt + 2097152, 1024, 1024);
  convT<<<dim3(16, 16), 256, 0, stream>>>(Wlin, Wt + 3145728, 1024, 1024);

  // 2. QKV projections (head-major bf16 epilogue)
  GemmArgs gq;
  gq.A = Xb;   gq.Bt = Wt;  gq.C = QKV;  gq.Cf = nullptr;
  gq.sA = 1024; gq.sB = 1024; gq.sC = 0;
  gq.zA = 0;    gq.zB = 1048576; gq.zC = 8388608;
  gq.K = 1024;  gq.ltemp = nullptr; gq.mode = 1;
  gemm_bt<<<dim3(8, 64, 3), 256, 0, stream>>>(gq);

  // 3. depthwise conv on K,V
  dwconv<<<dim3(16384), 256, 0, stream>>>(QKV + 8388608, cw, Kc, Vc);

  // 4. Vc -> Vct ([bh][64][1024])
  transpose2d<<<dim3(1, 16, 32), 256, 0, stream>>>(Vc, Vct, 1024, 64);

  // 5. logits = Qh @ Kc^T * exp(-lt) -> f32 output 1
  GemmArgs gl;
  gl.A = QKV;  gl.Bt = Kc;  gl.C = nullptr;  gl.Cf = logits_f;
  gl.sA = 64;  gl.sB = 64;  gl.sC = 1024;
  gl.zA = 262144; gl.zB = 65536; gl.zC = 4194304;
  gl.K = 64;   gl.ltemp = lt; gl.mode = 0;
  gemm_bt<<<dim3(8, 32, 32), 256, 0, stream>>>(gl);

  // 6. softmax + PV -> oattn bf16 [8192][1024]
  softmax_pv<<<dim3(128, 32), 256, 0, stream>>>(logits_f, Vct, oattn);

  // 7. out = oattn @ Wlin -> f32 output 0
  GemmArgs gf;
  gf.A = oattn; gf.Bt = Wt + 3145728; gf.C = nullptr; gf.Cf = out_f;
  gf.sA = 1024; gf.sB = 1024; gf.sC = 1024;
  gf.zA = 0;    gf.zB = 0;    gf.zC = 0;
  gf.K = 1024;  gf.ltemp = nullptr; gf.mode = 0;
  gemm_bt<<<dim3(8, 64, 1), 256, 0, stream>>>(gf);
}